// Round 2
// baseline (550.072 us; speedup 1.0000x reference)
//
#include <hip/hip_runtime.h>
#include <hip/hip_bf16.h>

// Problem constants (from reference): B=4, L=2048, H=8, D=64, SAMPLE_K=N_TOP=40
#define BB 4
#define LL 2048
#define HH 8
#define DD 64
#define SK 40
#define NT 40

// ---------------------------------------------------------------------------
// Kernel 1: M[bh][l] = max_s(q . k_{idx[l,s]}) - (sum_s q . k_{idx[l,s]}) / L
// One wave (64 lanes) per (b,h,l) row; lane = d.
// ---------------------------------------------------------------------------
__global__ void compute_m_kernel(const float* __restrict__ Q,
                                 const float* __restrict__ K,
                                 const int* __restrict__ idx,
                                 float* __restrict__ M) {
    int w    = blockIdx.x * 4 + (threadIdx.x >> 6);   // row id in [0, B*H*L)
    int lane = threadIdx.x & 63;
    int l  = w & (LL - 1);
    int bh = w >> 11;            // L = 2048
    int h  = bh & (HH - 1);
    int b  = bh >> 3;

    // Q[b, l, h, lane]
    float q = Q[(((size_t)b * LL + l) * HH + h) * DD + lane];
    const size_t kbase = ((size_t)b * LL * HH + h) * DD;   // + kk*H*D + lane

    float mx = -INFINITY;
    float sm = 0.0f;
    const int* ip = idx + (size_t)l * SK;
    for (int s = 0; s < SK; ++s) {
        int kk = ip[s];
        float kd = K[kbase + (size_t)kk * HH * DD + lane];
        float p = q * kd;
        #pragma unroll
        for (int off = 32; off >= 1; off >>= 1)
            p += __shfl_xor(p, off, 64);
        mx = fmaxf(mx, p);
        sm += p;
    }
    if (lane == 0)
        M[(size_t)bh * LL + l] = mx - sm * (1.0f / (float)LL);
}

// ---------------------------------------------------------------------------
// Kernel 2: top-40 (descending, lower index wins ties) per (b,h).
// One block of 256 threads per bh; iterative argmax with removal.
// ---------------------------------------------------------------------------
__global__ void topk_kernel(const float* __restrict__ M, int* __restrict__ topi) {
    __shared__ float sm[LL];
    __shared__ float rv[256];
    __shared__ int   ri[256];
    int bh = blockIdx.x;
    int t  = threadIdx.x;

    for (int i = t; i < LL; i += 256) sm[i] = M[(size_t)bh * LL + i];
    __syncthreads();

    for (int u = 0; u < NT; ++u) {
        float bv = -INFINITY;
        int   bi = LL;
        for (int i = t; i < LL; i += 256) {
            float v = sm[i];
            if (v > bv || (v == bv && i < bi)) { bv = v; bi = i; }
        }
        rv[t] = bv; ri[t] = bi;
        __syncthreads();
        for (int stp = 128; stp >= 1; stp >>= 1) {
            if (t < stp) {
                float ov = rv[t + stp]; int oi = ri[t + stp];
                if (ov > rv[t] || (ov == rv[t] && oi < ri[t])) { rv[t] = ov; ri[t] = oi; }
            }
            __syncthreads();
        }
        if (t == 0) {
            topi[bh * NT + u] = ri[0];
            sm[ri[0]] = -INFINITY;
        }
        __syncthreads();
    }
}

// ---------------------------------------------------------------------------
// Kernel 3: for each (b,h,u): scores = q_top . K^T * 1/8 ; softmax ; . V
// One block of 256 threads per (b,h,u). Scores live in LDS (2048 f32).
// ---------------------------------------------------------------------------
__global__ void attn_kernel(const float* __restrict__ Q,
                            const float* __restrict__ K,
                            const float* __restrict__ V,
                            const int* __restrict__ topi,
                            float* __restrict__ out) {
    __shared__ float qs[DD];
    __shared__ float sc[LL];
    __shared__ float red[256];

    int x  = blockIdx.x;
    int u  = x % NT;
    int bh = x / NT;
    int h  = bh & (HH - 1);
    int b  = bh >> 3;
    int t  = threadIdx.x;

    int lq = topi[bh * NT + u];
    if (t < DD)
        qs[t] = Q[(((size_t)b * LL + lq) * HH + h) * DD + t];
    __syncthreads();

    const float* Kb = K + ((size_t)b * LL * HH + h) * DD;
    // --- scores ---
    for (int k = t; k < LL; k += 256) {
        const float4* kr4 = reinterpret_cast<const float4*>(Kb + (size_t)k * HH * DD);
        float dot = 0.0f;
        #pragma unroll
        for (int c = 0; c < 16; ++c) {
            float4 p = kr4[c];
            dot += qs[4 * c + 0] * p.x;
            dot += qs[4 * c + 1] * p.y;
            dot += qs[4 * c + 2] * p.z;
            dot += qs[4 * c + 3] * p.w;
        }
        sc[k] = dot * 0.125f;   // 1/sqrt(64)
    }
    __syncthreads();

    // --- softmax: max ---
    float lm = -INFINITY;
    for (int k = t; k < LL; k += 256) lm = fmaxf(lm, sc[k]);
    red[t] = lm;
    __syncthreads();
    for (int stp = 128; stp >= 1; stp >>= 1) {
        if (t < stp) red[t] = fmaxf(red[t], red[t + stp]);
        __syncthreads();
    }
    float mx = red[0];
    __syncthreads();

    // --- softmax: exp + sum ---
    float ls = 0.0f;
    for (int k = t; k < LL; k += 256) {
        float e = __expf(sc[k] - mx);
        sc[k] = e;
        ls += e;
    }
    red[t] = ls;
    __syncthreads();
    for (int stp = 128; stp >= 1; stp >>= 1) {
        if (t < stp) red[t] += red[t + stp];
        __syncthreads();
    }
    float inv = 1.0f / red[0];
    __syncthreads();   // before reusing red

    // --- context: out[d] = sum_k sc[k] * V[b,k,h,d] ---
    int d  = t & 63;
    int qk = t >> 6;          // 4 key-chunks of 512
    const float* Vb = V + ((size_t)b * LL * HH + h) * DD;
    float acc = 0.0f;
    for (int k = qk * 512; k < qk * 512 + 512; ++k)
        acc += sc[k] * Vb[(size_t)k * HH * DD + d];
    red[t] = acc;
    __syncthreads();
    if (t < 64) {
        float r = red[t] + red[t + 64] + red[t + 128] + red[t + 192];
        out[(((size_t)b * NT + u) * HH + h) * DD + d] = r * inv;
    }
}

extern "C" void kernel_launch(void* const* d_in, const int* in_sizes, int n_in,
                              void* d_out, int out_size, void* d_ws, size_t ws_size,
                              hipStream_t stream) {
    const float* Q   = (const float*)d_in[0];
    const float* K   = (const float*)d_in[1];
    const float* V   = (const float*)d_in[2];
    const int*   idx = (const int*)d_in[3];
    float* out = (float*)d_out;

    float* M    = (float*)d_ws;                                    // B*H*L floats = 256 KB
    int*   topi = (int*)((char*)d_ws + (size_t)BB * HH * LL * sizeof(float)); // B*H*NT ints

    hipLaunchKernelGGL(compute_m_kernel, dim3(BB * HH * LL / 4), dim3(256), 0, stream,
                       Q, K, idx, M);
    hipLaunchKernelGGL(topk_kernel, dim3(BB * HH), dim3(256), 0, stream, M, topi);
    hipLaunchKernelGGL(attn_kernel, dim3(BB * HH * NT), dim3(256), 0, stream,
                       Q, K, V, topi, out);
}

// Round 3
// 255.367 us; speedup vs baseline: 2.1540x; 2.1540x over previous
//
#include <hip/hip_runtime.h>
#include <hip/hip_bf16.h>

// Problem constants: B=4, L=2048, H=8, D=64, SAMPLE_K=N_TOP=40
#define BB 4
#define LL 2048
#define HH 8
#define DD 64
#define SK 40
#define NT 40
#define CH 256              // keys per attn block
#define NCH (LL / CH)       // 8 chunks per (b,h)

// ---------------------------------------------------------------------------
// Kernel 1: M[bh][l] = max_s(q . k_{idx[l,s]}) - (sum_s q . k_{idx[l,s]}) / L
// One wave per (b,h,l); lane s (<40) computes the full 64-dot for sample s.
// One butterfly reduction per row (not per sample).
// ---------------------------------------------------------------------------
__global__ __launch_bounds__(256) void compute_m_kernel(
        const float* __restrict__ Q, const float* __restrict__ K,
        const int* __restrict__ idx, float* __restrict__ M) {
    __shared__ float qs[4][DD];
    int w    = blockIdx.x * 4 + (threadIdx.x >> 6);
    int lane = threadIdx.x & 63;
    int wv   = threadIdx.x >> 6;
    int l  = w & (LL - 1);
    int bh = w >> 11;
    int h  = bh & (HH - 1);
    int b  = bh >> 3;

    qs[wv][lane] = Q[(((size_t)b * LL + l) * HH + h) * DD + lane];
    __syncthreads();

    int kk = idx[(size_t)l * SK + (lane < SK ? lane : 0)];
    const float4* kr = (const float4*)&K[(((size_t)b * LL + kk) * HH + h) * DD];
    const float4* q4 = (const float4*)&qs[wv][0];
    float dot = 0.0f;
    #pragma unroll
    for (int c = 0; c < 16; ++c) {
        float4 qv = q4[c], kv = kr[c];
        dot += qv.x * kv.x + qv.y * kv.y + qv.z * kv.z + qv.w * kv.w;
    }
    float dm = (lane < SK) ? dot : -INFINITY;
    float ds = (lane < SK) ? dot : 0.0f;
    #pragma unroll
    for (int off = 32; off >= 1; off >>= 1) {
        dm = fmaxf(dm, __shfl_xor(dm, off, 64));
        ds += __shfl_xor(ds, off, 64);
    }
    if (lane == 0)
        M[(size_t)bh * LL + l] = dm - ds * (1.0f / (float)LL);
}

// ---------------------------------------------------------------------------
// Kernel 2: top-40 per (b,h), lower index wins ties.
// Packed key: (ordered_float << 11) | (2047 - i); integer max == desired order.
// ---------------------------------------------------------------------------
__global__ __launch_bounds__(256) void topk_kernel(const float* __restrict__ M,
                                                   int* __restrict__ topi) {
    __shared__ unsigned long long keys[LL];   // 16 KB
    __shared__ unsigned long long wmax[4];
    int bh = blockIdx.x;
    int t  = threadIdx.x;
    int lane = t & 63, w = t >> 6;

    for (int i = t; i < LL; i += 256) {
        unsigned int bits = __float_as_uint(M[(size_t)bh * LL + i]);
        bits = (bits & 0x80000000u) ? ~bits : (bits | 0x80000000u);
        keys[i] = ((unsigned long long)bits << 11) | (unsigned int)(LL - 1 - i);
    }
    __syncthreads();

    for (int u = 0; u < NT; ++u) {
        unsigned long long k = keys[t];
        #pragma unroll
        for (int j = 1; j < 8; ++j) {
            unsigned long long o = keys[t + 256 * j];
            if (o > k) k = o;
        }
        #pragma unroll
        for (int off = 32; off >= 1; off >>= 1) {
            unsigned long long o = __shfl_xor(k, off, 64);
            if (o > k) k = o;
        }
        if (lane == 0) wmax[w] = k;
        __syncthreads();
        if (t == 0) {
            unsigned long long k0 = wmax[0], k1 = wmax[1], k2 = wmax[2], k3 = wmax[3];
            if (k1 > k0) k0 = k1;
            if (k3 > k2) k2 = k3;
            if (k2 > k0) k0 = k2;
            int i = (LL - 1) - (int)(k0 & 0x7FF);
            topi[bh * NT + u] = i;
            keys[i] = 0ULL;   // remove (0 < any finite key)
        }
        __syncthreads();
    }
}

// ---------------------------------------------------------------------------
// Kernel 3: flash-chunked attention. Block = (b,h,chunk of 256 keys), 4 waves.
// Wave owns 64 keys: K row in 16 float4 regs, V column (d=lane) in 64 regs.
// All 40 queries per wave; u processed in quads to amortize V reads.
// Emits per-chunk (m, l, o[64]) partials.
// ---------------------------------------------------------------------------
__global__ __launch_bounds__(256) void attn_kernel(
        const float* __restrict__ Q, const float* __restrict__ K,
        const float* __restrict__ V, const int* __restrict__ topi,
        float* __restrict__ pm, float* __restrict__ pl, float* __restrict__ po) {
    __shared__ float  qs[NT][DD];        // 10240 B
    __shared__ float4 e4buf[4][64];      //  4096 B
    __shared__ float  oarea[4][NT][DD];  // 40960 B
    __shared__ float  mlarea[4][NT][2];  //  1280 B

    int blk = blockIdx.x;
    int c   = blk % NCH;
    int bh  = blk / NCH;
    int h = bh & (HH - 1), b = bh >> 3;
    int t = threadIdx.x, lane = t & 63, w = t >> 6;

    // stage 40 q rows
    for (int i = t; i < NT * DD; i += 256) {
        int u = i >> 6, d = i & 63;
        int lq = topi[bh * NT + u];
        qs[u][d] = Q[(((size_t)b * LL + lq) * HH + h) * DD + d];
    }

    // K row for this lane's key -> registers
    int key = c * CH + w * 64 + lane;
    const float4* kr = (const float4*)&K[(((size_t)b * LL + key) * HH + h) * DD];
    float4 kreg[16];
    #pragma unroll
    for (int j = 0; j < 16; ++j) kreg[j] = kr[j];

    // V column (d = lane) for this wave's 64 keys -> registers (coalesced)
    float vcol[64];
    const float* vb = &V[(((size_t)b * LL + c * CH + w * 64) * HH + h) * DD + lane];
    #pragma unroll
    for (int j = 0; j < 64; ++j) vcol[j] = vb[(size_t)j * HH * DD];

    __syncthreads();   // qs ready

    for (int uq = 0; uq < NT / 4; ++uq) {
        float o0 = 0, o1 = 0, o2 = 0, o3 = 0;
        float mv0, mv1, mv2, mv3, lv0, lv1, lv2, lv3;
        float4 ev;
        #pragma unroll
        for (int j = 0; j < 4; ++j) {
            int u = uq * 4 + j;
            const float4* q4 = (const float4*)&qs[u][0];
            float s = 0.0f;
            #pragma unroll
            for (int cc = 0; cc < 16; ++cc) {
                float4 qv = q4[cc];
                s += qv.x * kreg[cc].x + qv.y * kreg[cc].y
                   + qv.z * kreg[cc].z + qv.w * kreg[cc].w;
            }
            s *= 0.125f;   // 1/sqrt(64)
            float m = s;
            #pragma unroll
            for (int off = 32; off >= 1; off >>= 1)
                m = fmaxf(m, __shfl_xor(m, off, 64));
            float e = __expf(s - m);
            float ls = e;
            #pragma unroll
            for (int off = 32; off >= 1; off >>= 1)
                ls += __shfl_xor(ls, off, 64);
            if (j == 0) { mv0 = m; lv0 = ls; ev.x = e; }
            if (j == 1) { mv1 = m; lv1 = ls; ev.y = e; }
            if (j == 2) { mv2 = m; lv2 = ls; ev.z = e; }
            if (j == 3) { mv3 = m; lv3 = ls; ev.w = e; }
        }
        e4buf[w][lane] = ev;
        asm volatile("s_waitcnt lgkmcnt(0)" ::: "memory");   // intra-wave LDS ordering
        #pragma unroll 8
        for (int l2 = 0; l2 < 64; ++l2) {
            float4 e = e4buf[w][l2];   // broadcast read
            float  v = vcol[l2];
            o0 += e.x * v; o1 += e.y * v; o2 += e.z * v; o3 += e.w * v;
        }
        oarea[w][uq * 4 + 0][lane] = o0;
        oarea[w][uq * 4 + 1][lane] = o1;
        oarea[w][uq * 4 + 2][lane] = o2;
        oarea[w][uq * 4 + 3][lane] = o3;
        if (lane == 0) {
            mlarea[w][uq * 4 + 0][0] = mv0; mlarea[w][uq * 4 + 0][1] = lv0;
            mlarea[w][uq * 4 + 1][0] = mv1; mlarea[w][uq * 4 + 1][1] = lv1;
            mlarea[w][uq * 4 + 2][0] = mv2; mlarea[w][uq * 4 + 2][1] = lv2;
            mlarea[w][uq * 4 + 3][0] = mv3; mlarea[w][uq * 4 + 3][1] = lv3;
        }
    }
    __syncthreads();

    // combine 4 waves -> one chunk partial
    for (int i = t; i < NT * DD; i += 256) {
        int u = i >> 6, d = i & 63;
        float m0 = mlarea[0][u][0], m1 = mlarea[1][u][0];
        float m2 = mlarea[2][u][0], m3 = mlarea[3][u][0];
        float mb = fmaxf(fmaxf(m0, m1), fmaxf(m2, m3));
        float s0 = __expf(m0 - mb), s1 = __expf(m1 - mb);
        float s2 = __expf(m2 - mb), s3 = __expf(m3 - mb);
        float ob = oarea[0][u][d] * s0 + oarea[1][u][d] * s1
                 + oarea[2][u][d] * s2 + oarea[3][u][d] * s3;
        po[((size_t)(bh * NT + u) * NCH + c) * DD + d] = ob;
        if (d == 0) {
            float lb = mlarea[0][u][1] * s0 + mlarea[1][u][1] * s1
                     + mlarea[2][u][1] * s2 + mlarea[3][u][1] * s3;
            pm[(bh * NT + u) * NCH + c] = mb;
            pl[(bh * NT + u) * NCH + c] = lb;
        }
    }
}

// ---------------------------------------------------------------------------
// Kernel 4: merge chunk partials. One wave per (bh,u), lane = d.
// ---------------------------------------------------------------------------
__global__ __launch_bounds__(256) void merge_kernel(
        const float* __restrict__ pm, const float* __restrict__ pl,
        const float* __restrict__ po, float* __restrict__ out) {
    int wid  = blockIdx.x * 4 + (threadIdx.x >> 6);
    int lane = threadIdx.x & 63;
    int u  = wid % NT;
    int bh = wid / NT;
    int h = bh & (HH - 1), b = bh >> 3;
    int base = (bh * NT + u) * NCH;

    float m = -INFINITY;
    #pragma unroll
    for (int cc = 0; cc < NCH; ++cc) m = fmaxf(m, pm[base + cc]);
    float lsum = 0.0f, o = 0.0f;
    #pragma unroll
    for (int cc = 0; cc < NCH; ++cc) {
        float sc = __expf(pm[base + cc] - m);
        lsum += pl[base + cc] * sc;
        o    += po[(size_t)(base + cc) * DD + lane] * sc;
    }
    out[(((size_t)b * NT + u) * HH + h) * DD + lane] = o / lsum;
}

extern "C" void kernel_launch(void* const* d_in, const int* in_sizes, int n_in,
                              void* d_out, int out_size, void* d_ws, size_t ws_size,
                              hipStream_t stream) {
    const float* Q   = (const float*)d_in[0];
    const float* K   = (const float*)d_in[1];
    const float* V   = (const float*)d_in[2];
    const int*   idx = (const int*)d_in[3];
    float* out = (float*)d_out;

    char* ws = (char*)d_ws;
    float* M    = (float*)ws;                         ws += (size_t)BB * HH * LL * sizeof(float);   // 256 KB
    int*   topi = (int*)ws;                           ws += (size_t)BB * HH * NT * sizeof(int);     // 5 KB
    float* pm   = (float*)ws;                         ws += (size_t)BB * HH * NT * NCH * sizeof(float);
    float* pl   = (float*)ws;                         ws += (size_t)BB * HH * NT * NCH * sizeof(float);
    float* po   = (float*)ws;                         // 32*40*8*64*4 = 2.62 MB

    hipLaunchKernelGGL(compute_m_kernel, dim3(BB * HH * LL / 4), dim3(256), 0, stream,
                       Q, K, idx, M);
    hipLaunchKernelGGL(topk_kernel, dim3(BB * HH), dim3(256), 0, stream, M, topi);
    hipLaunchKernelGGL(attn_kernel, dim3(BB * HH * NCH), dim3(256), 0, stream,
                       Q, K, V, topi, pm, pl, po);
    hipLaunchKernelGGL(merge_kernel, dim3(BB * HH * NT / 4), dim3(256), 0, stream,
                       pm, pl, po, out);
}

// Round 4
// 235.760 us; speedup vs baseline: 2.3332x; 1.0832x over previous
//
#include <hip/hip_runtime.h>
#include <hip/hip_bf16.h>

// Problem constants: B=4, L=2048, H=8, D=64, SAMPLE_K=N_TOP=40
#define BB 4
#define LL 2048
#define HH 8
#define DD 64
#define SK 40
#define NT 40
#define CH 256              // keys per attn block
#define NCH (LL / CH)       // 8 chunks per (b,h)

// ---------------------------------------------------------------------------
// Kernel 1: M[bh][l] = max_s(q . k_{idx[l,s]}) - (sum_s q . k_{idx[l,s]}) / L
// One block (256 thr) per (b,l): all 8 heads together. K[b,kk,:,:] is 2 KB
// contiguous -> each sample gather is ONE fully-coalesced 2-KB block read
// (thread t reads float2 at kk*256+t). Dot per head: 5-step butterfly within
// each 32-lane half-group (h = t>>5, j = t&31).
// ---------------------------------------------------------------------------
__global__ __launch_bounds__(256) void compute_m_kernel(
        const float* __restrict__ Q, const float* __restrict__ K,
        const int* __restrict__ idx, float* __restrict__ M) {
    __shared__ int sidx[SK];
    int blk = blockIdx.x;
    int l = blk & (LL - 1);
    int b = blk >> 11;
    int t = threadIdx.x;
    int h = t >> 5, j = t & 31;

    if (t < SK) sidx[t] = idx[(size_t)l * SK + t];

    // Q[b,l,h,2j], Q[b,l,h,2j+1]  (512 floats contiguous per (b,l))
    const float2* Q2 = (const float2*)Q + ((size_t)b * LL + l) * 256;
    float2 qv = Q2[t];

    const float2* K2 = (const float2*)K + (size_t)b * LL * 256;
    __syncthreads();

    float mx = -INFINITY;
    float sm = 0.0f;
    #pragma unroll 8
    for (int s = 0; s < SK; ++s) {
        int kk = sidx[s];
        float2 kv = K2[(size_t)kk * 256 + t];
        float p = qv.x * kv.x + qv.y * kv.y;
        #pragma unroll
        for (int off = 16; off >= 1; off >>= 1)
            p += __shfl_xor(p, off, 64);
        mx = fmaxf(mx, p);
        sm += p;
    }
    if (j == 0)
        M[((size_t)b * HH + h) * LL + l] = mx - sm * (1.0f / (float)LL);
}

// ---------------------------------------------------------------------------
// Kernel 2: top-40 per (b,h), lower index wins ties.
// Packed key: (ordered_float << 11) | (2047 - i); integer max == desired order.
// ---------------------------------------------------------------------------
__global__ __launch_bounds__(256) void topk_kernel(const float* __restrict__ M,
                                                   int* __restrict__ topi) {
    __shared__ unsigned long long keys[LL];   // 16 KB
    __shared__ unsigned long long wmax[4];
    int bh = blockIdx.x;
    int t  = threadIdx.x;
    int lane = t & 63, w = t >> 6;

    for (int i = t; i < LL; i += 256) {
        unsigned int bits = __float_as_uint(M[(size_t)bh * LL + i]);
        bits = (bits & 0x80000000u) ? ~bits : (bits | 0x80000000u);
        keys[i] = ((unsigned long long)bits << 11) | (unsigned int)(LL - 1 - i);
    }
    __syncthreads();

    for (int u = 0; u < NT; ++u) {
        unsigned long long k = keys[t];
        #pragma unroll
        for (int j = 1; j < 8; ++j) {
            unsigned long long o = keys[t + 256 * j];
            if (o > k) k = o;
        }
        #pragma unroll
        for (int off = 32; off >= 1; off >>= 1) {
            unsigned long long o = __shfl_xor(k, off, 64);
            if (o > k) k = o;
        }
        if (lane == 0) wmax[w] = k;
        __syncthreads();
        if (t == 0) {
            unsigned long long k0 = wmax[0], k1 = wmax[1], k2 = wmax[2], k3 = wmax[3];
            if (k1 > k0) k0 = k1;
            if (k3 > k2) k2 = k3;
            if (k2 > k0) k0 = k2;
            int i = (LL - 1) - (int)(k0 & 0x7FF);
            topi[bh * NT + u] = i;
            keys[i] = 0ULL;   // remove (0 < any finite key)
        }
        __syncthreads();
    }
}

// ---------------------------------------------------------------------------
// Kernel 3: flash-chunked attention. Block = (b,h,chunk of 256 keys), 4 waves.
// Wave owns 64 keys: K row in 16 float4 regs, V column (d=lane) in 64 regs.
// All 40 queries per wave; u processed in quads to amortize V reads.
// Emits per-chunk (m, l, o[64]) partials.
// ---------------------------------------------------------------------------
__global__ __launch_bounds__(256) void attn_kernel(
        const float* __restrict__ Q, const float* __restrict__ K,
        const float* __restrict__ V, const int* __restrict__ topi,
        float* __restrict__ pm, float* __restrict__ pl, float* __restrict__ po) {
    __shared__ float  qs[NT][DD];        // 10240 B
    __shared__ float4 e4buf[4][64];      //  4096 B
    __shared__ float  oarea[4][NT][DD];  // 40960 B
    __shared__ float  mlarea[4][NT][2];  //  1280 B

    int blk = blockIdx.x;
    int c   = blk % NCH;
    int bh  = blk / NCH;
    int h = bh & (HH - 1), b = bh >> 3;
    int t = threadIdx.x, lane = t & 63, w = t >> 6;

    // stage 40 q rows
    for (int i = t; i < NT * DD; i += 256) {
        int u = i >> 6, d = i & 63;
        int lq = topi[bh * NT + u];
        qs[u][d] = Q[(((size_t)b * LL + lq) * HH + h) * DD + d];
    }

    // K row for this lane's key -> registers
    int key = c * CH + w * 64 + lane;
    const float4* kr = (const float4*)&K[(((size_t)b * LL + key) * HH + h) * DD];
    float4 kreg[16];
    #pragma unroll
    for (int j = 0; j < 16; ++j) kreg[j] = kr[j];

    // V column (d = lane) for this wave's 64 keys -> registers (coalesced)
    float vcol[64];
    const float* vb = &V[(((size_t)b * LL + c * CH + w * 64) * HH + h) * DD + lane];
    #pragma unroll
    for (int j = 0; j < 64; ++j) vcol[j] = vb[(size_t)j * HH * DD];

    __syncthreads();   // qs ready

    for (int uq = 0; uq < NT / 4; ++uq) {
        float o0 = 0, o1 = 0, o2 = 0, o3 = 0;
        float mv0, mv1, mv2, mv3, lv0, lv1, lv2, lv3;
        float4 ev;
        #pragma unroll
        for (int j = 0; j < 4; ++j) {
            int u = uq * 4 + j;
            const float4* q4 = (const float4*)&qs[u][0];
            float s = 0.0f;
            #pragma unroll
            for (int cc = 0; cc < 16; ++cc) {
                float4 qv = q4[cc];
                s += qv.x * kreg[cc].x + qv.y * kreg[cc].y
                   + qv.z * kreg[cc].z + qv.w * kreg[cc].w;
            }
            s *= 0.125f;   // 1/sqrt(64)
            float m = s;
            #pragma unroll
            for (int off = 32; off >= 1; off >>= 1)
                m = fmaxf(m, __shfl_xor(m, off, 64));
            float e = __expf(s - m);
            float ls = e;
            #pragma unroll
            for (int off = 32; off >= 1; off >>= 1)
                ls += __shfl_xor(ls, off, 64);
            if (j == 0) { mv0 = m; lv0 = ls; ev.x = e; }
            if (j == 1) { mv1 = m; lv1 = ls; ev.y = e; }
            if (j == 2) { mv2 = m; lv2 = ls; ev.z = e; }
            if (j == 3) { mv3 = m; lv3 = ls; ev.w = e; }
        }
        e4buf[w][lane] = ev;
        asm volatile("s_waitcnt lgkmcnt(0)" ::: "memory");   // intra-wave LDS ordering
        #pragma unroll 8
        for (int l2 = 0; l2 < 64; ++l2) {
            float4 e = e4buf[w][l2];   // broadcast read
            float  v = vcol[l2];
            o0 += e.x * v; o1 += e.y * v; o2 += e.z * v; o3 += e.w * v;
        }
        oarea[w][uq * 4 + 0][lane] = o0;
        oarea[w][uq * 4 + 1][lane] = o1;
        oarea[w][uq * 4 + 2][lane] = o2;
        oarea[w][uq * 4 + 3][lane] = o3;
        if (lane == 0) {
            mlarea[w][uq * 4 + 0][0] = mv0; mlarea[w][uq * 4 + 0][1] = lv0;
            mlarea[w][uq * 4 + 1][0] = mv1; mlarea[w][uq * 4 + 1][1] = lv1;
            mlarea[w][uq * 4 + 2][0] = mv2; mlarea[w][uq * 4 + 2][1] = lv2;
            mlarea[w][uq * 4 + 3][0] = mv3; mlarea[w][uq * 4 + 3][1] = lv3;
        }
    }
    __syncthreads();

    // combine 4 waves -> one chunk partial
    for (int i = t; i < NT * DD; i += 256) {
        int u = i >> 6, d = i & 63;
        float m0 = mlarea[0][u][0], m1 = mlarea[1][u][0];
        float m2 = mlarea[2][u][0], m3 = mlarea[3][u][0];
        float mb = fmaxf(fmaxf(m0, m1), fmaxf(m2, m3));
        float s0 = __expf(m0 - mb), s1 = __expf(m1 - mb);
        float s2 = __expf(m2 - mb), s3 = __expf(m3 - mb);
        float ob = oarea[0][u][d] * s0 + oarea[1][u][d] * s1
                 + oarea[2][u][d] * s2 + oarea[3][u][d] * s3;
        po[((size_t)(bh * NT + u) * NCH + c) * DD + d] = ob;
        if (d == 0) {
            float lb = mlarea[0][u][1] * s0 + mlarea[1][u][1] * s1
                     + mlarea[2][u][1] * s2 + mlarea[3][u][1] * s3;
            pm[(bh * NT + u) * NCH + c] = mb;
            pl[(bh * NT + u) * NCH + c] = lb;
        }
    }
}

// ---------------------------------------------------------------------------
// Kernel 4: merge chunk partials. One wave per (bh,u), lane = d.
// ---------------------------------------------------------------------------
__global__ __launch_bounds__(256) void merge_kernel(
        const float* __restrict__ pm, const float* __restrict__ pl,
        const float* __restrict__ po, float* __restrict__ out) {
    int wid  = blockIdx.x * 4 + (threadIdx.x >> 6);
    int lane = threadIdx.x & 63;
    int u  = wid % NT;
    int bh = wid / NT;
    int h = bh & (HH - 1), b = bh >> 3;
    int base = (bh * NT + u) * NCH;

    float m = -INFINITY;
    #pragma unroll
    for (int cc = 0; cc < NCH; ++cc) m = fmaxf(m, pm[base + cc]);
    float lsum = 0.0f, o = 0.0f;
    #pragma unroll
    for (int cc = 0; cc < NCH; ++cc) {
        float sc = __expf(pm[base + cc] - m);
        lsum += pl[base + cc] * sc;
        o    += po[(size_t)(base + cc) * DD + lane] * sc;
    }
    out[(((size_t)b * NT + u) * HH + h) * DD + lane] = o / lsum;
}

extern "C" void kernel_launch(void* const* d_in, const int* in_sizes, int n_in,
                              void* d_out, int out_size, void* d_ws, size_t ws_size,
                              hipStream_t stream) {
    const float* Q   = (const float*)d_in[0];
    const float* K   = (const float*)d_in[1];
    const float* V   = (const float*)d_in[2];
    const int*   idx = (const int*)d_in[3];
    float* out = (float*)d_out;

    char* ws = (char*)d_ws;
    float* M    = (float*)ws;                         ws += (size_t)BB * HH * LL * sizeof(float);   // 256 KB
    int*   topi = (int*)ws;                           ws += (size_t)BB * HH * NT * sizeof(int);     // 5 KB
    float* pm   = (float*)ws;                         ws += (size_t)BB * HH * NT * NCH * sizeof(float);
    float* pl   = (float*)ws;                         ws += (size_t)BB * HH * NT * NCH * sizeof(float);
    float* po   = (float*)ws;                         // 32*40*8*64*4 = 2.62 MB

    hipLaunchKernelGGL(compute_m_kernel, dim3(BB * LL), dim3(256), 0, stream,
                       Q, K, idx, M);
    hipLaunchKernelGGL(topk_kernel, dim3(BB * HH), dim3(256), 0, stream, M, topi);
    hipLaunchKernelGGL(attn_kernel, dim3(BB * HH * NCH), dim3(256), 0, stream,
                       Q, K, V, topi, pm, pl, po);
    hipLaunchKernelGGL(merge_kernel, dim3(BB * HH * NT / 4), dim3(256), 0, stream,
                       pm, pl, po, out);
}